// Round 6
// baseline (1009.506 us; speedup 1.0000x reference)
//
#include <hip/hip_runtime.h>
#include <hip/hip_bf16.h>

// HINGE_56985626083396 — fused embedding-conv-BN-min-FC forward on MI355X.
//
// Round-6: fix round-5's spill regression. Evidence: WRITE_SIZE 16->427 MB,
// VGPR_Count 76->64 (allocator squeezed under launch_bounds(256,4)'s 128-reg
// unified cap; acc 64 AGPR + frags 32 + prefetch 32 + addr ~20 = ~150 > 128
// -> scratch spill in the K-loop). Fix: __launch_bounds__(256,3) (cap 170,
// spill-free, 3 blocks/CU). KEEP round-5's two wins: XCD swizzle (FETCH
// 263->117 MB, gather re-reads now L2-local) and Ash-overlaid stats pad.
//
// Structure (hrt-sharing decomposition):
//   H[b,f]   = hrt . W2[:,0:768]            once, stored bf16
//   G1: [fv_k|fr0] . W1      (M=2B, K=512)  stats pass + min pass
//   T:  [kr_k|kv_k] . W2[:,768:] (M=4B,K=512) stats(+H) pass + final(+H) pass
// conv biases skipped: BN mean-subtraction cancels them exactly.

typedef __hip_bfloat16 bf16;
typedef short bf16x8 __attribute__((ext_vector_type(8)));   // 8 bf16 in 4 VGPRs
typedef float f32x4 __attribute__((ext_vector_type(4)));

#define BATCH 32768
#define MODE_STATS 0
#define MODE_MIN1  1
#define MODE_FINAL 2
#define MODE_STORE 3

__device__ __forceinline__ unsigned short f2b(float f) {
    union { float f; unsigned u; } v; v.f = f;
    unsigned r = v.u + 0x7fffu + ((v.u >> 16) & 1u);   // round-to-nearest-even
    return (unsigned short)(r >> 16);
}

__global__ __launch_bounds__(256)
void cvt_kernel(const float* __restrict__ src, unsigned short* __restrict__ dst, int n4)
{
    int i = blockIdx.x * 256 + threadIdx.x;
    if (i >= n4) return;
    float4 v = ((const float4*)src)[i];
    ushort4 h;
    h.x = f2b(v.x); h.y = f2b(v.y); h.z = f2b(v.z); h.w = f2b(v.w);
    ((ushort4*)dst)[i] = h;
}

// out[m,f] = sum_k A[m,k] * W[f, KWOFF+k],  W rows at stride KSTR (bf16).
// A rows gathered from embeddings; row m -> (b=m/RPB, kk=m%RPB); K in 256-wide
// segments. 128x128 tile, BK=64, 4 waves in 2x2 of 64x64.
// Grid is 1-D NT*4, swizzled: lin = s*32 + n*8 + r -> m_tile=s*8+r, n_tile=n:
// the 4 sibling n-tiles of a row-tile share lin%8 (same XCD round-robin) and
// sit <=31 dispatch slots apart -> gather re-reads hit the local L2.
template<int KLEN, int KSTR, int KWOFF, int RPB, int MODE, bool HADD, bool CVTA>
__global__ __launch_bounds__(256, 3)
void gemm_kernel(const int* __restrict__ x, const void* __restrict__ embR_,
                 const void* __restrict__ embV_, const bf16* __restrict__ W,
                 float* __restrict__ accum, const float* __restrict__ coef,
                 bf16* __restrict__ min1, bf16* __restrict__ Hbuf,
                 const float* __restrict__ fcw, float* __restrict__ outacc)
{
    constexpr int KOFF = (RPB == 2) ? 0 : 2;        // window offset in stats
    __shared__ __align__(16) short Ash[128 * 72];   // +8 pad; also reused as `red`
    __shared__ __align__(16) short Bsh[128 * 72];
    constexpr int NB = 128 / RPB;
    __shared__ int xsh[NB * 12];

    const int tid = threadIdx.x;
    const int lin = blockIdx.x;
    const int m_base = ((lin >> 5) * 8 + (lin & 7)) * 128;
    const int n_base = ((lin >> 3) & 3) * 128;
    const int b0 = m_base / RPB;

    for (int i = tid; i < NB * 12; i += 256) xsh[i] = x[b0 * 12 + i];
    __syncthreads();

    const int lane = tid & 63;
    const int wv   = tid >> 6;
    const int wmb  = (wv >> 1) * 64;
    const int wnb  = (wv & 1) * 64;
    const int quad = lane >> 4;
    const int l16  = lane & 15;

    f32x4 acc[4][4];
    #pragma unroll
    for (int i = 0; i < 4; ++i)
        #pragma unroll
        for (int j = 0; j < 4; ++j)
            acc[i][j] = (f32x4){0.f, 0.f, 0.f, 0.f};

    auto pick = [&](int row, int seg, int& idx, int& isRole) {
        if constexpr (RPB == 1) {               // H: hrt = [fv0|fr0|fv1]
            if      (seg == 0) { idx = xsh[row * 12 + 1]; isRole = 0; }
            else if (seg == 1) { idx = xsh[row * 12 + 0]; isRole = 1; }
            else               { idx = xsh[row * 12 + 3]; isRole = 0; }
        } else if constexpr (RPB == 2) {        // GEMM1: [fv_kk | fr0]
            int bl = row >> 1, kk = row & 1;
            if (seg == 0) { idx = xsh[bl * 12 + 2 * kk + 1]; isRole = 0; }
            else          { idx = xsh[bl * 12 + 0];          isRole = 1; }
        } else if constexpr (KLEN == 512) {     // T: [kr_kk | kv_kk]
            int bl = row >> 2, kk = row & 3;
            if (seg == 0) { idx = xsh[bl * 12 + 2 * kk + 4]; isRole = 1; }
            else          { idx = xsh[bl * 12 + 2 * kk + 5]; isRole = 0; }
        } else {                                // tier3 full win2
            int bl = row >> 2, kk = row & 3;
            switch (seg) {
                case 0:  idx = xsh[bl * 12 + 1];          isRole = 0; break;
                case 1:  idx = xsh[bl * 12 + 0];          isRole = 1; break;
                case 2:  idx = xsh[bl * 12 + 3];          isRole = 0; break;
                case 3:  idx = xsh[bl * 12 + 2 * kk + 4]; isRole = 1; break;
                default: idx = xsh[bl * 12 + 2 * kk + 5]; isRole = 0; break;
            }
        }
    };

    // Register prefetch of the A-chunk gather: issued one chunk ahead so the
    // (post-swizzle, mostly-L2) latency overlaps the MFMA phase.
    float4 preF[8];     // CVTA path (f32 gather)
    uint4  preB[4];     // bf16 path

    auto issueA = [&](int ch) {
        const int k0 = ch * 64, seg = k0 >> 8;
        if constexpr (CVTA) {
            const float* embRf = (const float*)embR_;
            const float* embVf = (const float*)embV_;
            const int so4 = (k0 & 255) >> 2;
            #pragma unroll
            for (int i = 0; i < 8; ++i) {
                int flat = tid + i * 256;           // 0..2047
                int row  = flat >> 4;
                int off4 = flat & 15;
                int idx, isRole;
                pick(row, seg, idx, isRole);
                const float* tab = isRole ? embRf : embVf;
                preF[i] = ((const float4*)(tab + (size_t)idx * 256))[so4 + off4];
            }
        } else {
            const bf16* embRb = (const bf16*)embR_;
            const bf16* embVb = (const bf16*)embV_;
            const int so8 = (k0 & 255) >> 3;
            #pragma unroll
            for (int i = 0; i < 4; ++i) {
                int flat = tid + i * 256;           // 0..1023
                int row  = flat >> 3;
                int off8 = flat & 7;
                int idx, isRole;
                pick(row, seg, idx, isRole);
                const bf16* tab = isRole ? embRb : embVb;
                preB[i] = ((const uint4*)(tab + (size_t)idx * 256))[so8 + off8];
            }
        }
    };
    auto writeA = [&]() {
        if constexpr (CVTA) {
            #pragma unroll
            for (int i = 0; i < 8; ++i) {
                int flat = tid + i * 256;
                int row  = flat >> 4;
                int off4 = flat & 15;
                ushort4 h;
                h.x = f2b(preF[i].x); h.y = f2b(preF[i].y);
                h.z = f2b(preF[i].z); h.w = f2b(preF[i].w);
                *(ushort4*)&Ash[row * 72 + off4 * 4] = h;
            }
        } else {
            #pragma unroll
            for (int i = 0; i < 4; ++i) {
                int flat = tid + i * 256;
                int row  = flat >> 3;
                int off8 = flat & 7;
                *(uint4*)&Ash[row * 72 + off8 * 8] = preB[i];
            }
        }
    };

    constexpr int NCH = KLEN / 64;
    issueA(0);
    for (int ch = 0; ch < NCH; ++ch) {
        {   // stage W first (L2-hot, short latency) — A prefetch keeps flying
            const int k0 = ch * 64;
            #pragma unroll
            for (int i = 0; i < 4; ++i) {
                int flat = tid + i * 256;
                int fr   = flat >> 3;
                int off8 = flat & 7;
                uint4 v = ((const uint4*)(W + (size_t)(n_base + fr) * KSTR + KWOFF + k0))[off8];
                *(uint4*)&Bsh[fr * 72 + off8 * 8] = v;
            }
        }
        writeA();                                   // waits on prefetched loads
        __syncthreads();
        if (ch + 1 < NCH) issueA(ch + 1);           // fly during MFMA phase

        #pragma unroll
        for (int ks = 0; ks < 64; ks += 32) {
            bf16x8 af[4], bf_[4];
            #pragma unroll
            for (int t = 0; t < 4; ++t)
                af[t]  = *(const bf16x8*)&Ash[(wmb + t * 16 + l16) * 72 + ks + quad * 8];
            #pragma unroll
            for (int t = 0; t < 4; ++t)
                bf_[t] = *(const bf16x8*)&Bsh[(wnb + t * 16 + l16) * 72 + ks + quad * 8];
            #pragma unroll
            for (int i = 0; i < 4; ++i)
                #pragma unroll
                for (int j = 0; j < 4; ++j)
                    acc[i][j] = __builtin_amdgcn_mfma_f32_16x16x32_bf16(
                        af[i], bf_[j], acc[i][j], 0, 0, 0);
        }
        __syncthreads();
    }

    // Epilogues. C/D layout: f(col) = l16, m(row) = quad*4 + reg.
    // m = m_base + wmb + i*16 + quad*4 + r;  f = n_base + wnb + j*16 + l16.
    if constexpr (MODE == MODE_STORE) {             // H store (RPB==1)
        #pragma unroll
        for (int j = 0; j < 4; ++j) {
            int f = n_base + wnb + j * 16 + l16;
            #pragma unroll
            for (int i = 0; i < 4; ++i)
                #pragma unroll
                for (int r = 0; r < 4; ++r) {
                    int m = m_base + wmb + i * 16 + quad * 4 + r;
                    *(unsigned short*)&Hbuf[(size_t)m * 512 + f] = f2b(acc[i][j][r]);
                }
        }
    } else if constexpr (MODE == MODE_STATS) {
        // Ash is dead past the final barrier — reuse as reduction pad (4KB saved)
        float* red = (float*)Ash;
        for (int i = tid; i < RPB * 256; i += 256) red[i] = 0.f;
        __syncthreads();
        #pragma unroll
        for (int j = 0; j < 4; ++j) {
            int fl = wnb + j * 16 + l16;
            float sr[4] = {0.f,0.f,0.f,0.f}, qr[4] = {0.f,0.f,0.f,0.f};
            #pragma unroll
            for (int i = 0; i < 4; ++i) {
                float h = 0.f;
                if constexpr (HADD) {               // RPB==4: one b per (i,quad)
                    int b = b0 + (wmb >> 2) + i * 4 + quad;
                    h = __bfloat162float(Hbuf[(size_t)b * 512 + n_base + fl]);
                }
                #pragma unroll
                for (int r = 0; r < 4; ++r) {
                    float v = acc[i][j][r] + h;
                    sr[r] += v; qr[r] += v * v;
                }
            }
            #pragma unroll
            for (int r = 0; r < 4; ++r) {
                int kk = r % RPB;
                atomicAdd(&red[kk * 128 + fl], sr[r]);
                atomicAdd(&red[RPB * 128 + kk * 128 + fl], qr[r]);
            }
        }
        __syncthreads();
        for (int idx = tid; idx < RPB * 128; idx += 256) {
            int kw = KOFF + (idx >> 7);
            int f  = n_base + (idx & 127);
            atomicAdd(&accum[kw * 512 + f], red[idx]);
            atomicAdd(&accum[3072 + kw * 512 + f], red[RPB * 128 + idx]);
        }
    } else if constexpr (MODE == MODE_MIN1) {       // RPB==2, windows 0,1
        #pragma unroll
        for (int j = 0; j < 4; ++j) {
            int f = n_base + wnb + j * 16 + l16;
            float a0 = coef[f],        c0 = coef[3072 + f];
            float a1 = coef[512 + f],  c1 = coef[3072 + 512 + f];
            #pragma unroll
            for (int i = 0; i < 4; ++i) {
                #pragma unroll
                for (int rp = 0; rp < 2; ++rp) {
                    int m = m_base + wmb + i * 16 + quad * 4 + rp * 2;
                    float v0 = fmaxf(a0 * acc[i][j][rp * 2]     + c0, 0.f);
                    float v1 = fmaxf(a1 * acc[i][j][rp * 2 + 1] + c1, 0.f);
                    *(unsigned short*)&min1[(size_t)(m >> 1) * 512 + f] =
                        f2b(fminf(v0, v1));
                }
            }
        }
    } else {  // MODE_FINAL: RPB==4, windows 2..5 in r=0..3
        float dotp[4] = {0.f, 0.f, 0.f, 0.f};
        #pragma unroll
        for (int j = 0; j < 4; ++j) {
            int f = n_base + wnb + j * 16 + l16;
            float a[4], c[4];
            #pragma unroll
            for (int r = 0; r < 4; ++r) {
                a[r] = coef[(2 + r) * 512 + f];
                c[r] = coef[3072 + (2 + r) * 512 + f];
            }
            float fw = fcw[f];
            #pragma unroll
            for (int i = 0; i < 4; ++i) {
                int b = b0 + (wmb >> 2) + i * 4 + quad;
                float h = 0.f;
                if constexpr (HADD)
                    h = __bfloat162float(Hbuf[(size_t)b * 512 + f]);
                float mv = 1e30f;
                #pragma unroll
                for (int r = 0; r < 4; ++r)
                    mv = fminf(mv, fmaxf(a[r] * (acc[i][j][r] + h) + c[r], 0.f));
                mv = fminf(mv, __bfloat162float(min1[(size_t)b * 512 + f]));
                dotp[i] += mv * fw;
            }
        }
        #pragma unroll
        for (int i = 0; i < 4; ++i) {
            float v = dotp[i];
            #pragma unroll
            for (int s = 8; s >= 1; s >>= 1) v += __shfl_xor(v, s);
            if (l16 == 0) {
                int b = b0 + (wmb >> 2) + i * 4 + quad;
                atomicAdd(&outacc[b], v);
            }
        }
    }
}

__global__ void bncoef_kernel(const float* __restrict__ accum,
                              const float* __restrict__ g1, const float* __restrict__ be1,
                              const float* __restrict__ g2, const float* __restrict__ be2,
                              float* __restrict__ coef)
{
    int id = blockIdx.x * 256 + threadIdx.x;
    if (id >= 3072) return;
    int kw = id >> 9, f = id & 511;
    float mean = accum[id] * (1.f / BATCH);
    float var  = accum[3072 + id] * (1.f / BATCH) - mean * mean;
    float g  = kw < 2 ? g1[f] : g2[f];
    float be = kw < 2 ? be1[f] : be2[f];
    float a  = g * rsqrtf(var + 1e-5f);
    coef[id] = a;
    coef[3072 + id] = be - a * mean;
}

__global__ void finish_kernel(const float* __restrict__ outacc,
                              const float* __restrict__ fcb, float* __restrict__ out)
{
    int b = blockIdx.x * 256 + threadIdx.x;
    if (b < BATCH)
        out[b] = outacc[b] + fcb[0];
}

extern "C" void kernel_launch(void* const* d_in, const int* in_sizes, int n_in,
                              void* d_out, int out_size, void* d_ws, size_t ws_size,
                              hipStream_t stream)
{
    (void)in_sizes; (void)n_in; (void)out_size;
    const int*   x    = (const int*)  d_in[0];
    const float* embR = (const float*)d_in[2];    // 50000 x 256 f32
    const float* embV = (const float*)d_in[3];    // 50000 x 256 f32
    const float* W1   = (const float*)d_in[4];    // 512 x 2 x 256 f32
    const float* g1   = (const float*)d_in[6];
    const float* be1  = (const float*)d_in[7];
    const float* W2   = (const float*)d_in[8];    // 512 x 5 x 256 f32
    const float* g2   = (const float*)d_in[10];
    const float* be2  = (const float*)d_in[11];
    const float* fcw  = (const float*)d_in[12];   // 512 f32
    const float* fcb  = (const float*)d_in[13];

    char* wsb = (char*)d_ws;
    float* accum  = (float*)wsb;                          //       0: 24 KB
    float* coef   = accum + 6144;                         //   24576: 24 KB
    float* outacc = coef + 6144;                          //   49152: 128 KB
    bf16*  Wbf1   = (bf16*)(wsb + 180224);                //  512 KB
    bf16*  Wbf2   = (bf16*)(wsb + 704512);                // 1.25 MB
    bf16*  Hbuf   = (bf16*)(wsb + 2015232);               // 32 MB (B*512 bf16)
    bf16*  min1   = (bf16*)(wsb + 35569664);              // 32 MB -> ends 69124096
    bf16*  embRb  = (bf16*)(wsb + 69124096);              // 24.4 MB
    bf16*  embVb  = (bf16*)(wsb + 94724096);              // ends 120324096
    bf16*  min3   = (bf16*)(wsb + 2015232);               // tier3 min1 (H slot)

    const int tier = (ws_size >= 120324096) ? 1 : (ws_size >= 69124096) ? 2 : 3;

    hipMemsetAsync(accum, 0, 6144 * sizeof(float), stream);
    hipMemsetAsync(outacc, 0, BATCH * sizeof(float), stream);
    cvt_kernel<<<256, 256, 0, stream>>>(W1, (unsigned short*)Wbf1, 65536);
    cvt_kernel<<<640, 256, 0, stream>>>(W2, (unsigned short*)Wbf2, 163840);

    if (tier == 1) {
        cvt_kernel<<<12500, 256, 0, stream>>>(embR, (unsigned short*)embRb, 3200000);
        cvt_kernel<<<12500, 256, 0, stream>>>(embV, (unsigned short*)embVb, 3200000);
        gemm_kernel<768, 1280, 0, 1, MODE_STORE, false, false><<<1024, 256, 0, stream>>>(
            x, embRb, embVb, Wbf2, nullptr, nullptr, nullptr, Hbuf, nullptr, nullptr);
        gemm_kernel<512, 512, 0, 2, MODE_STATS, false, false><<<2048, 256, 0, stream>>>(
            x, embRb, embVb, Wbf1, accum, nullptr, nullptr, nullptr, nullptr, nullptr);
        gemm_kernel<512, 1280, 768, 4, MODE_STATS, true, false><<<4096, 256, 0, stream>>>(
            x, embRb, embVb, Wbf2, accum, nullptr, nullptr, Hbuf, nullptr, nullptr);
        bncoef_kernel<<<12, 256, 0, stream>>>(accum, g1, be1, g2, be2, coef);
        gemm_kernel<512, 512, 0, 2, MODE_MIN1, false, false><<<2048, 256, 0, stream>>>(
            x, embRb, embVb, Wbf1, nullptr, coef, min1, nullptr, nullptr, nullptr);
        gemm_kernel<512, 1280, 768, 4, MODE_FINAL, true, false><<<4096, 256, 0, stream>>>(
            x, embRb, embVb, Wbf2, nullptr, coef, min1, Hbuf, fcw, outacc);
    } else if (tier == 2) {
        gemm_kernel<768, 1280, 0, 1, MODE_STORE, false, true><<<1024, 256, 0, stream>>>(
            x, embR, embV, Wbf2, nullptr, nullptr, nullptr, Hbuf, nullptr, nullptr);
        gemm_kernel<512, 512, 0, 2, MODE_STATS, false, true><<<2048, 256, 0, stream>>>(
            x, embR, embV, Wbf1, accum, nullptr, nullptr, nullptr, nullptr, nullptr);
        gemm_kernel<512, 1280, 768, 4, MODE_STATS, true, true><<<4096, 256, 0, stream>>>(
            x, embR, embV, Wbf2, accum, nullptr, nullptr, Hbuf, nullptr, nullptr);
        bncoef_kernel<<<12, 256, 0, stream>>>(accum, g1, be1, g2, be2, coef);
        gemm_kernel<512, 512, 0, 2, MODE_MIN1, false, true><<<2048, 256, 0, stream>>>(
            x, embR, embV, Wbf1, nullptr, coef, min1, nullptr, nullptr, nullptr);
        gemm_kernel<512, 1280, 768, 4, MODE_FINAL, true, true><<<4096, 256, 0, stream>>>(
            x, embR, embV, Wbf2, nullptr, coef, min1, Hbuf, fcw, outacc);
    } else {  // tier3: monolithic K=1280 fallback (35.6 MB)
        gemm_kernel<512, 512, 0, 2, MODE_STATS, false, true><<<2048, 256, 0, stream>>>(
            x, embR, embV, Wbf1, accum, nullptr, nullptr, nullptr, nullptr, nullptr);
        gemm_kernel<1280, 1280, 0, 4, MODE_STATS, false, true><<<4096, 256, 0, stream>>>(
            x, embR, embV, Wbf2, accum, nullptr, nullptr, nullptr, nullptr, nullptr);
        bncoef_kernel<<<12, 256, 0, stream>>>(accum, g1, be1, g2, be2, coef);
        gemm_kernel<512, 512, 0, 2, MODE_MIN1, false, true><<<2048, 256, 0, stream>>>(
            x, embR, embV, Wbf1, nullptr, coef, min3, nullptr, nullptr, nullptr);
        gemm_kernel<1280, 1280, 0, 4, MODE_FINAL, false, true><<<4096, 256, 0, stream>>>(
            x, embR, embV, Wbf2, nullptr, coef, min3, nullptr, fcw, outacc);
    }
    finish_kernel<<<128, 256, 0, stream>>>(outacc, fcb, (float*)d_out);
}

// Round 7
// 1008.701 us; speedup vs baseline: 1.0008x; 1.0008x over previous
//
#include <hip/hip_runtime.h>
#include <hip/hip_bf16.h>

// HINGE_56985626083396 — fused embedding-conv-BN-min-FC forward on MI355X.
//
// Round-7: spill-free prefetch + bf16-table tier. Round-5/6 evidence: full
// 32-VGPR CVTA prefetch + 64-AGPR acc tile spills at any >=3 blocks/CU cap
// (WRITE_SIZE 427/242 MB scratch traffic). Fix: CVTA prefetches only HALF the
// A-chunk (preF[4]=16 VGPRs, ~160 total <= 170 cap @ (256,3)); bf16-table
// path full prefetch is only 16 VGPRs. KEEP: XCD swizzle (FETCH 263->95 MB),
// Ash-overlaid stats pad.
// New tier1.5 (ws>=86.8MB, inside the proven [69.1,120.3) bracket): emb
// tables pre-converted to bf16 for H/G1-stats/T-stats (half gather bytes, no
// cvt VALU); tables then dead -> min1 overlays them; MIN1/FINAL use f32 CVTA.
//
// Structure (hrt-sharing decomposition):
//   H[b,f]   = hrt . W2[:,0:768]            once, stored bf16
//   G1: [fv_k|fr0] . W1      (M=2B, K=512)  stats pass + min pass
//   T:  [kr_k|kv_k] . W2[:,768:] (M=4B,K=512) stats(+H) pass + final(+H) pass
// conv biases skipped: BN mean-subtraction cancels them exactly.

typedef __hip_bfloat16 bf16;
typedef short bf16x8 __attribute__((ext_vector_type(8)));   // 8 bf16 in 4 VGPRs
typedef float f32x4 __attribute__((ext_vector_type(4)));

#define BATCH 32768
#define MODE_STATS 0
#define MODE_MIN1  1
#define MODE_FINAL 2
#define MODE_STORE 3

__device__ __forceinline__ unsigned short f2b(float f) {
    union { float f; unsigned u; } v; v.f = f;
    unsigned r = v.u + 0x7fffu + ((v.u >> 16) & 1u);   // round-to-nearest-even
    return (unsigned short)(r >> 16);
}

__global__ __launch_bounds__(256)
void cvt_kernel(const float* __restrict__ src, unsigned short* __restrict__ dst, int n4)
{
    int i = blockIdx.x * 256 + threadIdx.x;
    if (i >= n4) return;
    float4 v = ((const float4*)src)[i];
    ushort4 h;
    h.x = f2b(v.x); h.y = f2b(v.y); h.z = f2b(v.z); h.w = f2b(v.w);
    ((ushort4*)dst)[i] = h;
}

// out[m,f] = sum_k A[m,k] * W[f, KWOFF+k],  W rows at stride KSTR (bf16).
// A rows gathered from embeddings; row m -> (b=m/RPB, kk=m%RPB); K in 256-wide
// segments. 128x128 tile, BK=64, 4 waves in 2x2 of 64x64.
// Grid swizzle: lin = s*32 + n*8 + r -> m_tile=s*8+r, n_tile=n: the 4 sibling
// n-tiles of a row-tile share lin%8 (same XCD) -> gather re-reads hit local L2.
template<int KLEN, int KSTR, int KWOFF, int RPB, int MODE, bool HADD, bool CVTA>
__global__ __launch_bounds__(256, 3)
void gemm_kernel(const int* __restrict__ x, const void* __restrict__ embR_,
                 const void* __restrict__ embV_, const bf16* __restrict__ W,
                 float* __restrict__ accum, const float* __restrict__ coef,
                 bf16* __restrict__ min1, bf16* __restrict__ Hbuf,
                 const float* __restrict__ fcw, float* __restrict__ outacc)
{
    constexpr int KOFF = (RPB == 2) ? 0 : 2;        // window offset in stats
    __shared__ __align__(16) short Ash[128 * 72];   // +8 pad; reused as `red`
    __shared__ __align__(16) short Bsh[128 * 72];
    constexpr int NB = 128 / RPB;
    __shared__ int xsh[NB * 12];

    const int tid = threadIdx.x;
    const int lin = blockIdx.x;
    const int m_base = ((lin >> 5) * 8 + (lin & 7)) * 128;
    const int n_base = ((lin >> 3) & 3) * 128;
    const int b0 = m_base / RPB;

    for (int i = tid; i < NB * 12; i += 256) xsh[i] = x[b0 * 12 + i];
    __syncthreads();

    const int lane = tid & 63;
    const int wv   = tid >> 6;
    const int wmb  = (wv >> 1) * 64;
    const int wnb  = (wv & 1) * 64;
    const int quad = lane >> 4;
    const int l16  = lane & 15;

    f32x4 acc[4][4];
    #pragma unroll
    for (int i = 0; i < 4; ++i)
        #pragma unroll
        for (int j = 0; j < 4; ++j)
            acc[i][j] = (f32x4){0.f, 0.f, 0.f, 0.f};

    auto pick = [&](int row, int seg, int& idx, int& isRole) {
        if constexpr (RPB == 1) {               // H: hrt = [fv0|fr0|fv1]
            if      (seg == 0) { idx = xsh[row * 12 + 1]; isRole = 0; }
            else if (seg == 1) { idx = xsh[row * 12 + 0]; isRole = 1; }
            else               { idx = xsh[row * 12 + 3]; isRole = 0; }
        } else if constexpr (RPB == 2) {        // GEMM1: [fv_kk | fr0]
            int bl = row >> 1, kk = row & 1;
            if (seg == 0) { idx = xsh[bl * 12 + 2 * kk + 1]; isRole = 0; }
            else          { idx = xsh[bl * 12 + 0];          isRole = 1; }
        } else if constexpr (KLEN == 512) {     // T: [kr_kk | kv_kk]
            int bl = row >> 2, kk = row & 3;
            if (seg == 0) { idx = xsh[bl * 12 + 2 * kk + 4]; isRole = 1; }
            else          { idx = xsh[bl * 12 + 2 * kk + 5]; isRole = 0; }
        } else {                                // tier3 full win2
            int bl = row >> 2, kk = row & 3;
            switch (seg) {
                case 0:  idx = xsh[bl * 12 + 1];          isRole = 0; break;
                case 1:  idx = xsh[bl * 12 + 0];          isRole = 1; break;
                case 2:  idx = xsh[bl * 12 + 3];          isRole = 0; break;
                case 3:  idx = xsh[bl * 12 + 2 * kk + 4]; isRole = 1; break;
                default: idx = xsh[bl * 12 + 2 * kk + 5]; isRole = 0; break;
            }
        }
    };

    // Prefetch registers, sized to fit the (256,3) 170-reg unified budget
    // alongside the 64-AGPR acc tile: 16 VGPRs either path.
    float4 preF[4];     // CVTA: HALF the chunk (rows 0..63)
    uint4  preB[4];     // bf16: the whole chunk

    auto issueA = [&](int ch) {
        const int k0 = ch * 64, seg = k0 >> 8;
        if constexpr (CVTA) {
            const int so4 = (k0 & 255) >> 2;
            #pragma unroll
            for (int i = 0; i < 4; ++i) {
                int flat = tid + i * 256;           // rows 0..63
                int row  = flat >> 4;
                int off4 = flat & 15;
                int idx, isRole;
                pick(row, seg, idx, isRole);
                const float* tab = isRole ? (const float*)embR_ : (const float*)embV_;
                preF[i] = ((const float4*)(tab + (size_t)idx * 256))[so4 + off4];
            }
        } else {
            const int so8 = (k0 & 255) >> 3;
            #pragma unroll
            for (int i = 0; i < 4; ++i) {
                int flat = tid + i * 256;           // all 128 rows
                int row  = flat >> 3;
                int off8 = flat & 7;
                int idx, isRole;
                pick(row, seg, idx, isRole);
                const bf16* tab = isRole ? (const bf16*)embR_ : (const bf16*)embV_;
                preB[i] = ((const uint4*)(tab + (size_t)idx * 256))[so8 + off8];
            }
        }
    };
    auto writeA = [&](int ch) {
        if constexpr (CVTA) {
            #pragma unroll
            for (int i = 0; i < 4; ++i) {           // prefetched half
                int flat = tid + i * 256;
                int row  = flat >> 4;
                int off4 = flat & 15;
                ushort4 h;
                h.x = f2b(preF[i].x); h.y = f2b(preF[i].y);
                h.z = f2b(preF[i].z); h.w = f2b(preF[i].w);
                *(ushort4*)&Ash[row * 72 + off4 * 4] = h;
            }
            const int k0 = ch * 64, seg = k0 >> 8;
            const int so4 = (k0 & 255) >> 2;
            #pragma unroll
            for (int i = 4; i < 8; ++i) {           // direct half (rows 64..127)
                int flat = tid + i * 256;
                int row  = flat >> 4;
                int off4 = flat & 15;
                int idx, isRole;
                pick(row, seg, idx, isRole);
                const float* tab = isRole ? (const float*)embR_ : (const float*)embV_;
                float4 v = ((const float4*)(tab + (size_t)idx * 256))[so4 + off4];
                ushort4 h;
                h.x = f2b(v.x); h.y = f2b(v.y); h.z = f2b(v.z); h.w = f2b(v.w);
                *(ushort4*)&Ash[row * 72 + off4 * 4] = h;
            }
        } else {
            #pragma unroll
            for (int i = 0; i < 4; ++i) {
                int flat = tid + i * 256;
                int row  = flat >> 3;
                int off8 = flat & 7;
                *(uint4*)&Ash[row * 72 + off8 * 8] = preB[i];
            }
        }
    };

    constexpr int NCH = KLEN / 64;
    issueA(0);
    for (int ch = 0; ch < NCH; ++ch) {
        {   // stage W (L2-hot, short latency) while A prefetch flies
            const int k0 = ch * 64;
            #pragma unroll
            for (int i = 0; i < 4; ++i) {
                int flat = tid + i * 256;
                int fr   = flat >> 3;
                int off8 = flat & 7;
                uint4 v = ((const uint4*)(W + (size_t)(n_base + fr) * KSTR + KWOFF + k0))[off8];
                *(uint4*)&Bsh[fr * 72 + off8 * 8] = v;
            }
        }
        writeA(ch);
        __syncthreads();
        if (ch + 1 < NCH) issueA(ch + 1);           // fly during MFMA phase

        #pragma unroll
        for (int ks = 0; ks < 64; ks += 32) {
            bf16x8 af[4], bf_[4];
            #pragma unroll
            for (int t = 0; t < 4; ++t)
                af[t]  = *(const bf16x8*)&Ash[(wmb + t * 16 + l16) * 72 + ks + quad * 8];
            #pragma unroll
            for (int t = 0; t < 4; ++t)
                bf_[t] = *(const bf16x8*)&Bsh[(wnb + t * 16 + l16) * 72 + ks + quad * 8];
            #pragma unroll
            for (int i = 0; i < 4; ++i)
                #pragma unroll
                for (int j = 0; j < 4; ++j)
                    acc[i][j] = __builtin_amdgcn_mfma_f32_16x16x32_bf16(
                        af[i], bf_[j], acc[i][j], 0, 0, 0);
        }
        __syncthreads();
    }

    // Epilogues. C/D layout: f(col) = l16, m(row) = quad*4 + reg.
    // m = m_base + wmb + i*16 + quad*4 + r;  f = n_base + wnb + j*16 + l16.
    if constexpr (MODE == MODE_STORE) {             // H store (RPB==1)
        #pragma unroll
        for (int j = 0; j < 4; ++j) {
            int f = n_base + wnb + j * 16 + l16;
            #pragma unroll
            for (int i = 0; i < 4; ++i)
                #pragma unroll
                for (int r = 0; r < 4; ++r) {
                    int m = m_base + wmb + i * 16 + quad * 4 + r;
                    *(unsigned short*)&Hbuf[(size_t)m * 512 + f] = f2b(acc[i][j][r]);
                }
        }
    } else if constexpr (MODE == MODE_STATS) {
        float* red = (float*)Ash;                   // Ash dead past last barrier
        for (int i = tid; i < RPB * 256; i += 256) red[i] = 0.f;
        __syncthreads();
        #pragma unroll
        for (int j = 0; j < 4; ++j) {
            int fl = wnb + j * 16 + l16;
            float sr[4] = {0.f,0.f,0.f,0.f}, qr[4] = {0.f,0.f,0.f,0.f};
            #pragma unroll
            for (int i = 0; i < 4; ++i) {
                float h = 0.f;
                if constexpr (HADD) {               // RPB==4: one b per (i,quad)
                    int b = b0 + (wmb >> 2) + i * 4 + quad;
                    h = __bfloat162float(Hbuf[(size_t)b * 512 + n_base + fl]);
                }
                #pragma unroll
                for (int r = 0; r < 4; ++r) {
                    float v = acc[i][j][r] + h;
                    sr[r] += v; qr[r] += v * v;
                }
            }
            #pragma unroll
            for (int r = 0; r < 4; ++r) {
                int kk = r % RPB;
                atomicAdd(&red[kk * 128 + fl], sr[r]);
                atomicAdd(&red[RPB * 128 + kk * 128 + fl], qr[r]);
            }
        }
        __syncthreads();
        for (int idx = tid; idx < RPB * 128; idx += 256) {
            int kw = KOFF + (idx >> 7);
            int f  = n_base + (idx & 127);
            atomicAdd(&accum[kw * 512 + f], red[idx]);
            atomicAdd(&accum[3072 + kw * 512 + f], red[RPB * 128 + idx]);
        }
    } else if constexpr (MODE == MODE_MIN1) {       // RPB==2, windows 0,1
        #pragma unroll
        for (int j = 0; j < 4; ++j) {
            int f = n_base + wnb + j * 16 + l16;
            float a0 = coef[f],        c0 = coef[3072 + f];
            float a1 = coef[512 + f],  c1 = coef[3072 + 512 + f];
            #pragma unroll
            for (int i = 0; i < 4; ++i) {
                #pragma unroll
                for (int rp = 0; rp < 2; ++rp) {
                    int m = m_base + wmb + i * 16 + quad * 4 + rp * 2;
                    float v0 = fmaxf(a0 * acc[i][j][rp * 2]     + c0, 0.f);
                    float v1 = fmaxf(a1 * acc[i][j][rp * 2 + 1] + c1, 0.f);
                    *(unsigned short*)&min1[(size_t)(m >> 1) * 512 + f] =
                        f2b(fminf(v0, v1));
                }
            }
        }
    } else {  // MODE_FINAL: RPB==4, windows 2..5 in r=0..3
        float dotp[4] = {0.f, 0.f, 0.f, 0.f};
        #pragma unroll
        for (int j = 0; j < 4; ++j) {
            int f = n_base + wnb + j * 16 + l16;
            float a[4], c[4];
            #pragma unroll
            for (int r = 0; r < 4; ++r) {
                a[r] = coef[(2 + r) * 512 + f];
                c[r] = coef[3072 + (2 + r) * 512 + f];
            }
            float fw = fcw[f];
            #pragma unroll
            for (int i = 0; i < 4; ++i) {
                int b = b0 + (wmb >> 2) + i * 4 + quad;
                float h = 0.f;
                if constexpr (HADD)
                    h = __bfloat162float(Hbuf[(size_t)b * 512 + f]);
                float mv = 1e30f;
                #pragma unroll
                for (int r = 0; r < 4; ++r)
                    mv = fminf(mv, fmaxf(a[r] * (acc[i][j][r] + h) + c[r], 0.f));
                mv = fminf(mv, __bfloat162float(min1[(size_t)b * 512 + f]));
                dotp[i] += mv * fw;
            }
        }
        #pragma unroll
        for (int i = 0; i < 4; ++i) {
            float v = dotp[i];
            #pragma unroll
            for (int s = 8; s >= 1; s >>= 1) v += __shfl_xor(v, s);
            if (l16 == 0) {
                int b = b0 + (wmb >> 2) + i * 4 + quad;
                atomicAdd(&outacc[b], v);
            }
        }
    }
}

__global__ void bncoef_kernel(const float* __restrict__ accum,
                              const float* __restrict__ g1, const float* __restrict__ be1,
                              const float* __restrict__ g2, const float* __restrict__ be2,
                              float* __restrict__ coef)
{
    int id = blockIdx.x * 256 + threadIdx.x;
    if (id >= 3072) return;
    int kw = id >> 9, f = id & 511;
    float mean = accum[id] * (1.f / BATCH);
    float var  = accum[3072 + id] * (1.f / BATCH) - mean * mean;
    float g  = kw < 2 ? g1[f] : g2[f];
    float be = kw < 2 ? be1[f] : be2[f];
    float a  = g * rsqrtf(var + 1e-5f);
    coef[id] = a;
    coef[3072 + id] = be - a * mean;
}

__global__ void finish_kernel(const float* __restrict__ outacc,
                              const float* __restrict__ fcb, float* __restrict__ out)
{
    int b = blockIdx.x * 256 + threadIdx.x;
    if (b < BATCH)
        out[b] = outacc[b] + fcb[0];
}

extern "C" void kernel_launch(void* const* d_in, const int* in_sizes, int n_in,
                              void* d_out, int out_size, void* d_ws, size_t ws_size,
                              hipStream_t stream)
{
    (void)in_sizes; (void)n_in; (void)out_size;
    const int*   x    = (const int*)  d_in[0];
    const float* embR = (const float*)d_in[2];    // 50000 x 256 f32
    const float* embV = (const float*)d_in[3];    // 50000 x 256 f32
    const float* W1   = (const float*)d_in[4];    // 512 x 2 x 256 f32
    const float* g1   = (const float*)d_in[6];
    const float* be1  = (const float*)d_in[7];
    const float* W2   = (const float*)d_in[8];    // 512 x 5 x 256 f32
    const float* g2   = (const float*)d_in[10];
    const float* be2  = (const float*)d_in[11];
    const float* fcw  = (const float*)d_in[12];   // 512 f32
    const float* fcb  = (const float*)d_in[13];

    char* wsb = (char*)d_ws;
    float* accum  = (float*)wsb;                          //       0: 24 KB
    float* coef   = accum + 6144;                         //   24576: 24 KB
    float* outacc = coef + 6144;                          //   49152: 128 KB
    bf16*  Wbf1   = (bf16*)(wsb + 180224);                //  512 KB
    bf16*  Wbf2   = (bf16*)(wsb + 704512);                // 1.25 MB
    bf16*  Hbuf   = (bf16*)(wsb + 2015232);               // 32 MB (B*512 bf16)
    // tier1 layout (>=120.3 MB): min1 | embRb | embVb
    bf16*  min1   = (bf16*)(wsb + 35569664);              // 32 MB -> 69124096
    bf16*  embRb1 = (bf16*)(wsb + 69124096);              // 24.4 MB
    bf16*  embVb1 = (bf16*)(wsb + 94724096);              // -> 120324096
    // tier1.5 layout (>=86.8 MB): embRb | embVb, min1 overlays them after stats
    bf16*  embRb5 = (bf16*)(wsb + 35569664);              // 24.4 MB -> 61169664
    bf16*  embVb5 = (bf16*)(wsb + 61169664);              // 24.4 MB -> 86769664
    bf16*  min15  = (bf16*)(wsb + 35569664);              // overlays dead tables
    bf16*  min3   = (bf16*)(wsb + 2015232);               // tier3 (H slot)

    const int tier = (ws_size >= 120324096) ? 1
                   : (ws_size >=  86769664) ? 15
                   : (ws_size >=  69124096) ? 2 : 3;

    hipMemsetAsync(accum, 0, 6144 * sizeof(float), stream);
    hipMemsetAsync(outacc, 0, BATCH * sizeof(float), stream);
    cvt_kernel<<<256, 256, 0, stream>>>(W1, (unsigned short*)Wbf1, 65536);
    cvt_kernel<<<640, 256, 0, stream>>>(W2, (unsigned short*)Wbf2, 163840);

    if (tier == 1) {
        cvt_kernel<<<12500, 256, 0, stream>>>(embR, (unsigned short*)embRb1, 3200000);
        cvt_kernel<<<12500, 256, 0, stream>>>(embV, (unsigned short*)embVb1, 3200000);
        gemm_kernel<768, 1280, 0, 1, MODE_STORE, false, false><<<1024, 256, 0, stream>>>(
            x, embRb1, embVb1, Wbf2, nullptr, nullptr, nullptr, Hbuf, nullptr, nullptr);
        gemm_kernel<512, 512, 0, 2, MODE_STATS, false, false><<<2048, 256, 0, stream>>>(
            x, embRb1, embVb1, Wbf1, accum, nullptr, nullptr, nullptr, nullptr, nullptr);
        gemm_kernel<512, 1280, 768, 4, MODE_STATS, true, false><<<4096, 256, 0, stream>>>(
            x, embRb1, embVb1, Wbf2, accum, nullptr, nullptr, Hbuf, nullptr, nullptr);
        bncoef_kernel<<<12, 256, 0, stream>>>(accum, g1, be1, g2, be2, coef);
        gemm_kernel<512, 512, 0, 2, MODE_MIN1, false, false><<<2048, 256, 0, stream>>>(
            x, embRb1, embVb1, Wbf1, nullptr, coef, min1, nullptr, nullptr, nullptr);
        gemm_kernel<512, 1280, 768, 4, MODE_FINAL, true, false><<<4096, 256, 0, stream>>>(
            x, embRb1, embVb1, Wbf2, nullptr, coef, min1, Hbuf, fcw, outacc);
    } else if (tier == 15) {
        cvt_kernel<<<12500, 256, 0, stream>>>(embR, (unsigned short*)embRb5, 3200000);
        cvt_kernel<<<12500, 256, 0, stream>>>(embV, (unsigned short*)embVb5, 3200000);
        gemm_kernel<768, 1280, 0, 1, MODE_STORE, false, false><<<1024, 256, 0, stream>>>(
            x, embRb5, embVb5, Wbf2, nullptr, nullptr, nullptr, Hbuf, nullptr, nullptr);
        gemm_kernel<512, 512, 0, 2, MODE_STATS, false, false><<<2048, 256, 0, stream>>>(
            x, embRb5, embVb5, Wbf1, accum, nullptr, nullptr, nullptr, nullptr, nullptr);
        gemm_kernel<512, 1280, 768, 4, MODE_STATS, true, false><<<4096, 256, 0, stream>>>(
            x, embRb5, embVb5, Wbf2, accum, nullptr, nullptr, Hbuf, nullptr, nullptr);
        bncoef_kernel<<<12, 256, 0, stream>>>(accum, g1, be1, g2, be2, coef);
        // tables dead from here; min15 overlays them; gathers revert to f32
        gemm_kernel<512, 512, 0, 2, MODE_MIN1, false, true><<<2048, 256, 0, stream>>>(
            x, embR, embV, Wbf1, nullptr, coef, min15, nullptr, nullptr, nullptr);
        gemm_kernel<512, 1280, 768, 4, MODE_FINAL, true, true><<<4096, 256, 0, stream>>>(
            x, embR, embV, Wbf2, nullptr, coef, min15, Hbuf, fcw, outacc);
    } else if (tier == 2) {
        gemm_kernel<768, 1280, 0, 1, MODE_STORE, false, true><<<1024, 256, 0, stream>>>(
            x, embR, embV, Wbf2, nullptr, nullptr, nullptr, Hbuf, nullptr, nullptr);
        gemm_kernel<512, 512, 0, 2, MODE_STATS, false, true><<<2048, 256, 0, stream>>>(
            x, embR, embV, Wbf1, accum, nullptr, nullptr, nullptr, nullptr, nullptr);
        gemm_kernel<512, 1280, 768, 4, MODE_STATS, true, true><<<4096, 256, 0, stream>>>(
            x, embR, embV, Wbf2, accum, nullptr, nullptr, Hbuf, nullptr, nullptr);
        bncoef_kernel<<<12, 256, 0, stream>>>(accum, g1, be1, g2, be2, coef);
        gemm_kernel<512, 512, 0, 2, MODE_MIN1, false, true><<<2048, 256, 0, stream>>>(
            x, embR, embV, Wbf1, nullptr, coef, min1, nullptr, nullptr, nullptr);
        gemm_kernel<512, 1280, 768, 4, MODE_FINAL, true, true><<<4096, 256, 0, stream>>>(
            x, embR, embV, Wbf2, nullptr, coef, min1, Hbuf, fcw, outacc);
    } else {  // tier3: monolithic K=1280 fallback (35.6 MB)
        gemm_kernel<512, 512, 0, 2, MODE_STATS, false, true><<<2048, 256, 0, stream>>>(
            x, embR, embV, Wbf1, accum, nullptr, nullptr, nullptr, nullptr, nullptr);
        gemm_kernel<1280, 1280, 0, 4, MODE_STATS, false, true><<<4096, 256, 0, stream>>>(
            x, embR, embV, Wbf2, accum, nullptr, nullptr, nullptr, nullptr, nullptr);
        bncoef_kernel<<<12, 256, 0, stream>>>(accum, g1, be1, g2, be2, coef);
        gemm_kernel<512, 512, 0, 2, MODE_MIN1, false, true><<<2048, 256, 0, stream>>>(
            x, embR, embV, Wbf1, nullptr, coef, min3, nullptr, nullptr, nullptr);
        gemm_kernel<1280, 1280, 0, 4, MODE_FINAL, false, true><<<4096, 256, 0, stream>>>(
            x, embR, embV, Wbf2, nullptr, coef, min3, nullptr, fcw, outacc);
    }
    finish_kernel<<<128, 256, 0, stream>>>(outacc, fcb, (float*)d_out);
}

// Round 8
// 910.329 us; speedup vs baseline: 1.1089x; 1.1081x over previous
//
#include <hip/hip_runtime.h>
#include <hip/hip_bf16.h>

// HINGE_56985626083396 — fused embedding-conv-BN-min-FC forward on MI355X.
//
// Round-8: spill-free + swizzle. Evidence from r5-r7: ANY register prefetch
// held across the barrier + ANY launch_bounds squeeze spills the K-loop
// (WRITE_SIZE 427/242/244 MB scratch traffic, dur 282->346 us). Round-4's
// direct staging (VGPR 76 + 64 AGPR = 140 unified, spill-free, 3 blk/CU) is
// the proven-good register shape. This round = round-4 staging + round-5's
// XCD swizzle (FETCH 263->95 MB, gather re-reads hit local L2) + Ash-overlay
// stats pad. No prefetch, no launch-bounds minimum.
//
// Structure (hrt-sharing decomposition):
//   H[b,f]   = hrt . W2[:,0:768]            once, stored bf16
//   G1: [fv_k|fr0] . W1      (M=2B, K=512)  stats pass + min pass
//   T:  [kr_k|kv_k] . W2[:,768:] (M=4B,K=512) stats(+H) pass + final(+H) pass
// conv biases skipped: BN mean-subtraction cancels them exactly.
// ws bracket proven: [69.1, 86.8) MB -> tier2 operative (f32 CVTA staging).

typedef __hip_bfloat16 bf16;
typedef short bf16x8 __attribute__((ext_vector_type(8)));   // 8 bf16 in 4 VGPRs
typedef float f32x4 __attribute__((ext_vector_type(4)));

#define BATCH 32768
#define MODE_STATS 0
#define MODE_MIN1  1
#define MODE_FINAL 2
#define MODE_STORE 3

__device__ __forceinline__ unsigned short f2b(float f) {
    union { float f; unsigned u; } v; v.f = f;
    unsigned r = v.u + 0x7fffu + ((v.u >> 16) & 1u);   // round-to-nearest-even
    return (unsigned short)(r >> 16);
}

__global__ __launch_bounds__(256)
void cvt_kernel(const float* __restrict__ src, unsigned short* __restrict__ dst, int n4)
{
    int i = blockIdx.x * 256 + threadIdx.x;
    if (i >= n4) return;
    float4 v = ((const float4*)src)[i];
    ushort4 h;
    h.x = f2b(v.x); h.y = f2b(v.y); h.z = f2b(v.z); h.w = f2b(v.w);
    ((ushort4*)dst)[i] = h;
}

// out[m,f] = sum_k A[m,k] * W[f, KWOFF+k],  W rows at stride KSTR (bf16).
// A rows gathered from embeddings; row m -> (b=m/RPB, kk=m%RPB); K in 256-wide
// segments. 128x128 tile, BK=64, 4 waves in 2x2 of 64x64.
// Grid swizzle: lin = s*32 + n*8 + r -> m_tile=s*8+r, n_tile=n: the 4 sibling
// n-tiles of a row-tile share lin%8 (same XCD) -> gather re-reads hit local L2.
template<int KLEN, int KSTR, int KWOFF, int RPB, int MODE, bool HADD, bool CVTA>
__global__ __launch_bounds__(256)
void gemm_kernel(const int* __restrict__ x, const void* __restrict__ embR_,
                 const void* __restrict__ embV_, const bf16* __restrict__ W,
                 float* __restrict__ accum, const float* __restrict__ coef,
                 bf16* __restrict__ min1, bf16* __restrict__ Hbuf,
                 const float* __restrict__ fcw, float* __restrict__ outacc)
{
    constexpr int KOFF = (RPB == 2) ? 0 : 2;        // window offset in stats
    __shared__ __align__(16) short Ash[128 * 72];   // +8 pad; reused as `red`
    __shared__ __align__(16) short Bsh[128 * 72];
    constexpr int NB = 128 / RPB;
    __shared__ int xsh[NB * 12];

    const int tid = threadIdx.x;
    const int lin = blockIdx.x;
    const int m_base = ((lin >> 5) * 8 + (lin & 7)) * 128;
    const int n_base = ((lin >> 3) & 3) * 128;
    const int b0 = m_base / RPB;

    for (int i = tid; i < NB * 12; i += 256) xsh[i] = x[b0 * 12 + i];
    __syncthreads();

    const int lane = tid & 63;
    const int wv   = tid >> 6;
    const int wmb  = (wv >> 1) * 64;
    const int wnb  = (wv & 1) * 64;
    const int quad = lane >> 4;
    const int l16  = lane & 15;

    f32x4 acc[4][4];
    #pragma unroll
    for (int i = 0; i < 4; ++i)
        #pragma unroll
        for (int j = 0; j < 4; ++j)
            acc[i][j] = (f32x4){0.f, 0.f, 0.f, 0.f};

    auto pick = [&](int row, int seg, int& idx, int& isRole) {
        if constexpr (RPB == 1) {               // H: hrt = [fv0|fr0|fv1]
            if      (seg == 0) { idx = xsh[row * 12 + 1]; isRole = 0; }
            else if (seg == 1) { idx = xsh[row * 12 + 0]; isRole = 1; }
            else               { idx = xsh[row * 12 + 3]; isRole = 0; }
        } else if constexpr (RPB == 2) {        // GEMM1: [fv_kk | fr0]
            int bl = row >> 1, kk = row & 1;
            if (seg == 0) { idx = xsh[bl * 12 + 2 * kk + 1]; isRole = 0; }
            else          { idx = xsh[bl * 12 + 0];          isRole = 1; }
        } else if constexpr (KLEN == 512) {     // T: [kr_kk | kv_kk]
            int bl = row >> 2, kk = row & 3;
            if (seg == 0) { idx = xsh[bl * 12 + 2 * kk + 4]; isRole = 1; }
            else          { idx = xsh[bl * 12 + 2 * kk + 5]; isRole = 0; }
        } else {                                // tier3 full win2
            int bl = row >> 2, kk = row & 3;
            switch (seg) {
                case 0:  idx = xsh[bl * 12 + 1];          isRole = 0; break;
                case 1:  idx = xsh[bl * 12 + 0];          isRole = 1; break;
                case 2:  idx = xsh[bl * 12 + 3];          isRole = 0; break;
                case 3:  idx = xsh[bl * 12 + 2 * kk + 4]; isRole = 1; break;
                default: idx = xsh[bl * 12 + 2 * kk + 5]; isRole = 0; break;
            }
        }
    };

    constexpr int NCH = KLEN / 64;
    for (int ch = 0; ch < NCH; ++ch) {
        const int k0  = ch * 64;
        const int seg = k0 >> 8;

        // ---- stage A direct (round-4 proven spill-free shape) ----
        if constexpr (CVTA) {
            const float* embRf = (const float*)embR_;
            const float* embVf = (const float*)embV_;
            const int so4 = (k0 & 255) >> 2;
            #pragma unroll
            for (int i = 0; i < 8; ++i) {
                int flat = tid + i * 256;           // 0..2047
                int row  = flat >> 4;
                int off4 = flat & 15;
                int idx, isRole;
                pick(row, seg, idx, isRole);
                const float* tab = isRole ? embRf : embVf;
                float4 v = ((const float4*)(tab + (size_t)idx * 256))[so4 + off4];
                ushort4 h;
                h.x = f2b(v.x); h.y = f2b(v.y); h.z = f2b(v.z); h.w = f2b(v.w);
                *(ushort4*)&Ash[row * 72 + off4 * 4] = h;
            }
        } else {
            const bf16* embRb = (const bf16*)embR_;
            const bf16* embVb = (const bf16*)embV_;
            const int so8 = (k0 & 255) >> 3;
            #pragma unroll
            for (int i = 0; i < 4; ++i) {
                int flat = tid + i * 256;           // 0..1023
                int row  = flat >> 3;
                int off8 = flat & 7;
                int idx, isRole;
                pick(row, seg, idx, isRole);
                const bf16* tab = isRole ? embRb : embVb;
                uint4 v = ((const uint4*)(tab + (size_t)idx * 256))[so8 + off8];
                *(uint4*)&Ash[row * 72 + off8 * 8] = v;
            }
        }
        // ---- stage B: W rows f in [n_base,+128), k-chunk [KWOFF+k0,+64) ----
        #pragma unroll
        for (int i = 0; i < 4; ++i) {
            int flat = tid + i * 256;
            int fr   = flat >> 3;
            int off8 = flat & 7;
            uint4 v = ((const uint4*)(W + (size_t)(n_base + fr) * KSTR + KWOFF + k0))[off8];
            *(uint4*)&Bsh[fr * 72 + off8 * 8] = v;
        }
        __syncthreads();

        #pragma unroll
        for (int ks = 0; ks < 64; ks += 32) {
            bf16x8 af[4], bf_[4];
            #pragma unroll
            for (int t = 0; t < 4; ++t)
                af[t]  = *(const bf16x8*)&Ash[(wmb + t * 16 + l16) * 72 + ks + quad * 8];
            #pragma unroll
            for (int t = 0; t < 4; ++t)
                bf_[t] = *(const bf16x8*)&Bsh[(wnb + t * 16 + l16) * 72 + ks + quad * 8];
            #pragma unroll
            for (int i = 0; i < 4; ++i)
                #pragma unroll
                for (int j = 0; j < 4; ++j)
                    acc[i][j] = __builtin_amdgcn_mfma_f32_16x16x32_bf16(
                        af[i], bf_[j], acc[i][j], 0, 0, 0);
        }
        __syncthreads();
    }

    // Epilogues. C/D layout: f(col) = l16, m(row) = quad*4 + reg.
    // m = m_base + wmb + i*16 + quad*4 + r;  f = n_base + wnb + j*16 + l16.
    if constexpr (MODE == MODE_STORE) {             // H store (RPB==1)
        #pragma unroll
        for (int j = 0; j < 4; ++j) {
            int f = n_base + wnb + j * 16 + l16;
            #pragma unroll
            for (int i = 0; i < 4; ++i)
                #pragma unroll
                for (int r = 0; r < 4; ++r) {
                    int m = m_base + wmb + i * 16 + quad * 4 + r;
                    *(unsigned short*)&Hbuf[(size_t)m * 512 + f] = f2b(acc[i][j][r]);
                }
        }
    } else if constexpr (MODE == MODE_STATS) {
        float* red = (float*)Ash;                   // Ash dead past last barrier
        for (int i = tid; i < RPB * 256; i += 256) red[i] = 0.f;
        __syncthreads();
        #pragma unroll
        for (int j = 0; j < 4; ++j) {
            int fl = wnb + j * 16 + l16;
            float sr[4] = {0.f,0.f,0.f,0.f}, qr[4] = {0.f,0.f,0.f,0.f};
            #pragma unroll
            for (int i = 0; i < 4; ++i) {
                float h = 0.f;
                if constexpr (HADD) {               // RPB==4: one b per (i,quad)
                    int b = b0 + (wmb >> 2) + i * 4 + quad;
                    h = __bfloat162float(Hbuf[(size_t)b * 512 + n_base + fl]);
                }
                #pragma unroll
                for (int r = 0; r < 4; ++r) {
                    float v = acc[i][j][r] + h;
                    sr[r] += v; qr[r] += v * v;
                }
            }
            #pragma unroll
            for (int r = 0; r < 4; ++r) {
                int kk = r % RPB;
                atomicAdd(&red[kk * 128 + fl], sr[r]);
                atomicAdd(&red[RPB * 128 + kk * 128 + fl], qr[r]);
            }
        }
        __syncthreads();
        for (int idx = tid; idx < RPB * 128; idx += 256) {
            int kw = KOFF + (idx >> 7);
            int f  = n_base + (idx & 127);
            atomicAdd(&accum[kw * 512 + f], red[idx]);
            atomicAdd(&accum[3072 + kw * 512 + f], red[RPB * 128 + idx]);
        }
    } else if constexpr (MODE == MODE_MIN1) {       // RPB==2, windows 0,1
        #pragma unroll
        for (int j = 0; j < 4; ++j) {
            int f = n_base + wnb + j * 16 + l16;
            float a0 = coef[f],        c0 = coef[3072 + f];
            float a1 = coef[512 + f],  c1 = coef[3072 + 512 + f];
            #pragma unroll
            for (int i = 0; i < 4; ++i) {
                #pragma unroll
                for (int rp = 0; rp < 2; ++rp) {
                    int m = m_base + wmb + i * 16 + quad * 4 + rp * 2;
                    float v0 = fmaxf(a0 * acc[i][j][rp * 2]     + c0, 0.f);
                    float v1 = fmaxf(a1 * acc[i][j][rp * 2 + 1] + c1, 0.f);
                    *(unsigned short*)&min1[(size_t)(m >> 1) * 512 + f] =
                        f2b(fminf(v0, v1));
                }
            }
        }
    } else {  // MODE_FINAL: RPB==4, windows 2..5 in r=0..3
        float dotp[4] = {0.f, 0.f, 0.f, 0.f};
        #pragma unroll
        for (int j = 0; j < 4; ++j) {
            int f = n_base + wnb + j * 16 + l16;
            float a[4], c[4];
            #pragma unroll
            for (int r = 0; r < 4; ++r) {
                a[r] = coef[(2 + r) * 512 + f];
                c[r] = coef[3072 + (2 + r) * 512 + f];
            }
            float fw = fcw[f];
            #pragma unroll
            for (int i = 0; i < 4; ++i) {
                int b = b0 + (wmb >> 2) + i * 4 + quad;
                float h = 0.f;
                if constexpr (HADD)
                    h = __bfloat162float(Hbuf[(size_t)b * 512 + f]);
                float mv = 1e30f;
                #pragma unroll
                for (int r = 0; r < 4; ++r)
                    mv = fminf(mv, fmaxf(a[r] * (acc[i][j][r] + h) + c[r], 0.f));
                mv = fminf(mv, __bfloat162float(min1[(size_t)b * 512 + f]));
                dotp[i] += mv * fw;
            }
        }
        #pragma unroll
        for (int i = 0; i < 4; ++i) {
            float v = dotp[i];
            #pragma unroll
            for (int s = 8; s >= 1; s >>= 1) v += __shfl_xor(v, s);
            if (l16 == 0) {
                int b = b0 + (wmb >> 2) + i * 4 + quad;
                atomicAdd(&outacc[b], v);
            }
        }
    }
}

__global__ void bncoef_kernel(const float* __restrict__ accum,
                              const float* __restrict__ g1, const float* __restrict__ be1,
                              const float* __restrict__ g2, const float* __restrict__ be2,
                              float* __restrict__ coef)
{
    int id = blockIdx.x * 256 + threadIdx.x;
    if (id >= 3072) return;
    int kw = id >> 9, f = id & 511;
    float mean = accum[id] * (1.f / BATCH);
    float var  = accum[3072 + id] * (1.f / BATCH) - mean * mean;
    float g  = kw < 2 ? g1[f] : g2[f];
    float be = kw < 2 ? be1[f] : be2[f];
    float a  = g * rsqrtf(var + 1e-5f);
    coef[id] = a;
    coef[3072 + id] = be - a * mean;
}

__global__ void finish_kernel(const float* __restrict__ outacc,
                              const float* __restrict__ fcb, float* __restrict__ out)
{
    int b = blockIdx.x * 256 + threadIdx.x;
    if (b < BATCH)
        out[b] = outacc[b] + fcb[0];
}

extern "C" void kernel_launch(void* const* d_in, const int* in_sizes, int n_in,
                              void* d_out, int out_size, void* d_ws, size_t ws_size,
                              hipStream_t stream)
{
    (void)in_sizes; (void)n_in; (void)out_size;
    const int*   x    = (const int*)  d_in[0];
    const float* embR = (const float*)d_in[2];    // 50000 x 256 f32
    const float* embV = (const float*)d_in[3];    // 50000 x 256 f32
    const float* W1   = (const float*)d_in[4];    // 512 x 2 x 256 f32
    const float* g1   = (const float*)d_in[6];
    const float* be1  = (const float*)d_in[7];
    const float* W2   = (const float*)d_in[8];    // 512 x 5 x 256 f32
    const float* g2   = (const float*)d_in[10];
    const float* be2  = (const float*)d_in[11];
    const float* fcw  = (const float*)d_in[12];   // 512 f32
    const float* fcb  = (const float*)d_in[13];

    char* wsb = (char*)d_ws;
    float* accum  = (float*)wsb;                          //       0: 24 KB
    float* coef   = accum + 6144;                         //   24576: 24 KB
    float* outacc = coef + 6144;                          //   49152: 128 KB
    bf16*  Wbf1   = (bf16*)(wsb + 180224);                //  512 KB
    bf16*  Wbf2   = (bf16*)(wsb + 704512);                // 1.25 MB
    bf16*  Hbuf   = (bf16*)(wsb + 2015232);               // 32 MB (B*512 bf16)
    bf16*  min1   = (bf16*)(wsb + 35569664);              // 32 MB -> 69124096
    bf16*  embRb1 = (bf16*)(wsb + 69124096);              // 24.4 MB (tier1 only)
    bf16*  embVb1 = (bf16*)(wsb + 94724096);              // -> 120324096
    bf16*  min3   = (bf16*)(wsb + 2015232);               // tier3 (H slot)

    const int tier = (ws_size >= 120324096) ? 1
                   : (ws_size >=  69124096) ? 2 : 3;

    hipMemsetAsync(accum, 0, 6144 * sizeof(float), stream);
    hipMemsetAsync(outacc, 0, BATCH * sizeof(float), stream);
    cvt_kernel<<<256, 256, 0, stream>>>(W1, (unsigned short*)Wbf1, 65536);
    cvt_kernel<<<640, 256, 0, stream>>>(W2, (unsigned short*)Wbf2, 163840);

    if (tier == 1) {
        cvt_kernel<<<12500, 256, 0, stream>>>(embR, (unsigned short*)embRb1, 3200000);
        cvt_kernel<<<12500, 256, 0, stream>>>(embV, (unsigned short*)embVb1, 3200000);
        gemm_kernel<768, 1280, 0, 1, MODE_STORE, false, false><<<1024, 256, 0, stream>>>(
            x, embRb1, embVb1, Wbf2, nullptr, nullptr, nullptr, Hbuf, nullptr, nullptr);
        gemm_kernel<512, 512, 0, 2, MODE_STATS, false, false><<<2048, 256, 0, stream>>>(
            x, embRb1, embVb1, Wbf1, accum, nullptr, nullptr, nullptr, nullptr, nullptr);
        gemm_kernel<512, 1280, 768, 4, MODE_STATS, true, false><<<4096, 256, 0, stream>>>(
            x, embRb1, embVb1, Wbf2, accum, nullptr, nullptr, Hbuf, nullptr, nullptr);
        bncoef_kernel<<<12, 256, 0, stream>>>(accum, g1, be1, g2, be2, coef);
        gemm_kernel<512, 512, 0, 2, MODE_MIN1, false, false><<<2048, 256, 0, stream>>>(
            x, embRb1, embVb1, Wbf1, nullptr, coef, min1, nullptr, nullptr, nullptr);
        gemm_kernel<512, 1280, 768, 4, MODE_FINAL, true, false><<<4096, 256, 0, stream>>>(
            x, embRb1, embVb1, Wbf2, nullptr, coef, min1, Hbuf, fcw, outacc);
    } else if (tier == 2) {
        gemm_kernel<768, 1280, 0, 1, MODE_STORE, false, true><<<1024, 256, 0, stream>>>(
            x, embR, embV, Wbf2, nullptr, nullptr, nullptr, Hbuf, nullptr, nullptr);
        gemm_kernel<512, 512, 0, 2, MODE_STATS, false, true><<<2048, 256, 0, stream>>>(
            x, embR, embV, Wbf1, accum, nullptr, nullptr, nullptr, nullptr, nullptr);
        gemm_kernel<512, 1280, 768, 4, MODE_STATS, true, true><<<4096, 256, 0, stream>>>(
            x, embR, embV, Wbf2, accum, nullptr, nullptr, Hbuf, nullptr, nullptr);
        bncoef_kernel<<<12, 256, 0, stream>>>(accum, g1, be1, g2, be2, coef);
        gemm_kernel<512, 512, 0, 2, MODE_MIN1, false, true><<<2048, 256, 0, stream>>>(
            x, embR, embV, Wbf1, nullptr, coef, min1, nullptr, nullptr, nullptr);
        gemm_kernel<512, 1280, 768, 4, MODE_FINAL, true, true><<<4096, 256, 0, stream>>>(
            x, embR, embV, Wbf2, nullptr, coef, min1, Hbuf, fcw, outacc);
    } else {  // tier3: monolithic K=1280 fallback (35.6 MB)
        gemm_kernel<512, 512, 0, 2, MODE_STATS, false, true><<<2048, 256, 0, stream>>>(
            x, embR, embV, Wbf1, accum, nullptr, nullptr, nullptr, nullptr, nullptr);
        gemm_kernel<1280, 1280, 0, 4, MODE_STATS, false, true><<<4096, 256, 0, stream>>>(
            x, embR, embV, Wbf2, accum, nullptr, nullptr, nullptr, nullptr, nullptr);
        bncoef_kernel<<<12, 256, 0, stream>>>(accum, g1, be1, g2, be2, coef);
        gemm_kernel<512, 512, 0, 2, MODE_MIN1, false, true><<<2048, 256, 0, stream>>>(
            x, embR, embV, Wbf1, nullptr, coef, min3, nullptr, nullptr, nullptr);
        gemm_kernel<1280, 1280, 0, 4, MODE_FINAL, false, true><<<4096, 256, 0, stream>>>(
            x, embR, embV, Wbf2, nullptr, coef, min3, nullptr, fcw, outacc);
    }
    finish_kernel<<<128, 256, 0, stream>>>(outacc, fcb, (float*)d_out);
}

// Round 9
// 799.148 us; speedup vs baseline: 1.2632x; 1.1391x over previous
//
#include <hip/hip_runtime.h>
#include <hip/hip_bf16.h>

// HINGE_56985626083396 — fused embedding-conv-BN-min-FC forward on MI355X.
//
// Round-9: occupancy via smaller acc tile. r8 baseline (910 us total, T=256us,
// spill-free, swizzled) is reg-capped at 3 blocks/CU (80 VGPR + 64 AGPR acc).
// Change: wave tile 64x64 -> 64x32 (block tile 128x64, 4 waves 2x2): acc 32
// AGPR, ~90 unified regs -> 5 waves/SIMD; LDS 29-34KB -> 5 blocks/CU. Target
// ~20 waves/CU (+66% latency hiding). A-traffic per MFMA doubles (8 siblings/
// row-tile) but is L2-local post-swizzle (HBM at 4.9%, headroom). Grid
// swizzle: lin = s*64 + n*8 + r -> m_tile = s*8+r, n_tile = n (8 siblings
// share lin%8 = same XCD, <=63 slots apart).
//
// Structure (hrt-sharing decomposition):
//   H[b,f]   = hrt . W2[:,0:768]            once, stored bf16
//   G1: [fv_k|fr0] . W1      (M=2B, K=512)  stats pass + min pass
//   T:  [kr_k|kv_k] . W2[:,768:] (M=4B,K=512) stats(+H) pass + final(+H) pass
// conv biases skipped: BN mean-subtraction cancels them exactly.
// ws bracket proven: [69.1, 86.8) MB -> tier2 operative (f32 CVTA staging).

typedef __hip_bfloat16 bf16;
typedef short bf16x8 __attribute__((ext_vector_type(8)));   // 8 bf16 in 4 VGPRs
typedef float f32x4 __attribute__((ext_vector_type(4)));

#define BATCH 32768
#define MODE_STATS 0
#define MODE_MIN1  1
#define MODE_FINAL 2
#define MODE_STORE 3

__device__ __forceinline__ unsigned short f2b(float f) {
    union { float f; unsigned u; } v; v.f = f;
    unsigned r = v.u + 0x7fffu + ((v.u >> 16) & 1u);   // round-to-nearest-even
    return (unsigned short)(r >> 16);
}

__global__ __launch_bounds__(256)
void cvt_kernel(const float* __restrict__ src, unsigned short* __restrict__ dst, int n4)
{
    int i = blockIdx.x * 256 + threadIdx.x;
    if (i >= n4) return;
    float4 v = ((const float4*)src)[i];
    ushort4 h;
    h.x = f2b(v.x); h.y = f2b(v.y); h.z = f2b(v.z); h.w = f2b(v.w);
    ((ushort4*)dst)[i] = h;
}

// out[m,f] = sum_k A[m,k] * W[f, KWOFF+k],  W rows at stride KSTR (bf16).
// A rows gathered from embeddings; row m -> (b=m/RPB, kk=m%RPB); K in 256-wide
// segments. Block tile 128x64, BK=64; 4 waves in 2x2, wave tile 64x32.
template<int KLEN, int KSTR, int KWOFF, int RPB, int MODE, bool HADD, bool CVTA>
__global__ __launch_bounds__(256)
void gemm_kernel(const int* __restrict__ x, const void* __restrict__ embR_,
                 const void* __restrict__ embV_, const bf16* __restrict__ W,
                 float* __restrict__ accum, const float* __restrict__ coef,
                 bf16* __restrict__ min1, bf16* __restrict__ Hbuf,
                 const float* __restrict__ fcw, float* __restrict__ outacc)
{
    constexpr int KOFF = (RPB == 2) ? 0 : 2;        // window offset in stats
    __shared__ __align__(16) short Ash[128 * 72];   // +8 pad; reused as `red`
    __shared__ __align__(16) short Bsh[64 * 72];
    constexpr int NB = 128 / RPB;
    __shared__ int xsh[NB * 12];

    const int tid = threadIdx.x;
    const int lin = blockIdx.x;
    const int m_base = ((lin >> 6) * 8 + (lin & 7)) * 128;
    const int n_base = ((lin >> 3) & 7) * 64;
    const int b0 = m_base / RPB;

    for (int i = tid; i < NB * 12; i += 256) xsh[i] = x[b0 * 12 + i];
    __syncthreads();

    const int lane = tid & 63;
    const int wv   = tid >> 6;
    const int wmb  = (wv >> 1) * 64;                // wave m-offset (0/64)
    const int wnb  = (wv & 1) * 32;                 // wave n-offset (0/32)
    const int quad = lane >> 4;
    const int l16  = lane & 15;

    f32x4 acc[4][2];
    #pragma unroll
    for (int i = 0; i < 4; ++i)
        #pragma unroll
        for (int j = 0; j < 2; ++j)
            acc[i][j] = (f32x4){0.f, 0.f, 0.f, 0.f};

    auto pick = [&](int row, int seg, int& idx, int& isRole) {
        if constexpr (RPB == 1) {               // H: hrt = [fv0|fr0|fv1]
            if      (seg == 0) { idx = xsh[row * 12 + 1]; isRole = 0; }
            else if (seg == 1) { idx = xsh[row * 12 + 0]; isRole = 1; }
            else               { idx = xsh[row * 12 + 3]; isRole = 0; }
        } else if constexpr (RPB == 2) {        // GEMM1: [fv_kk | fr0]
            int bl = row >> 1, kk = row & 1;
            if (seg == 0) { idx = xsh[bl * 12 + 2 * kk + 1]; isRole = 0; }
            else          { idx = xsh[bl * 12 + 0];          isRole = 1; }
        } else if constexpr (KLEN == 512) {     // T: [kr_kk | kv_kk]
            int bl = row >> 2, kk = row & 3;
            if (seg == 0) { idx = xsh[bl * 12 + 2 * kk + 4]; isRole = 1; }
            else          { idx = xsh[bl * 12 + 2 * kk + 5]; isRole = 0; }
        } else {                                // tier3 full win2
            int bl = row >> 2, kk = row & 3;
            switch (seg) {
                case 0:  idx = xsh[bl * 12 + 1];          isRole = 0; break;
                case 1:  idx = xsh[bl * 12 + 0];          isRole = 1; break;
                case 2:  idx = xsh[bl * 12 + 3];          isRole = 0; break;
                case 3:  idx = xsh[bl * 12 + 2 * kk + 4]; isRole = 1; break;
                default: idx = xsh[bl * 12 + 2 * kk + 5]; isRole = 0; break;
            }
        }
    };

    constexpr int NCH = KLEN / 64;
    for (int ch = 0; ch < NCH; ++ch) {
        const int k0  = ch * 64;
        const int seg = k0 >> 8;

        // ---- stage A direct (spill-free shape): 128 rows x 64 k ----
        if constexpr (CVTA) {
            const float* embRf = (const float*)embR_;
            const float* embVf = (const float*)embV_;
            const int so4 = (k0 & 255) >> 2;
            #pragma unroll
            for (int i = 0; i < 8; ++i) {
                int flat = tid + i * 256;           // 0..2047
                int row  = flat >> 4;
                int off4 = flat & 15;
                int idx, isRole;
                pick(row, seg, idx, isRole);
                const float* tab = isRole ? embRf : embVf;
                float4 v = ((const float4*)(tab + (size_t)idx * 256))[so4 + off4];
                ushort4 h;
                h.x = f2b(v.x); h.y = f2b(v.y); h.z = f2b(v.z); h.w = f2b(v.w);
                *(ushort4*)&Ash[row * 72 + off4 * 4] = h;
            }
        } else {
            const bf16* embRb = (const bf16*)embR_;
            const bf16* embVb = (const bf16*)embV_;
            const int so8 = (k0 & 255) >> 3;
            #pragma unroll
            for (int i = 0; i < 4; ++i) {
                int flat = tid + i * 256;           // 0..1023
                int row  = flat >> 3;
                int off8 = flat & 7;
                int idx, isRole;
                pick(row, seg, idx, isRole);
                const bf16* tab = isRole ? embRb : embVb;
                uint4 v = ((const uint4*)(tab + (size_t)idx * 256))[so8 + off8];
                *(uint4*)&Ash[row * 72 + off8 * 8] = v;
            }
        }
        // ---- stage B: W rows f in [n_base,+64), k-chunk [KWOFF+k0,+64) ----
        #pragma unroll
        for (int i = 0; i < 2; ++i) {
            int flat = tid + i * 256;               // 0..511
            int fr   = flat >> 3;                   // 0..63
            int off8 = flat & 7;
            uint4 v = ((const uint4*)(W + (size_t)(n_base + fr) * KSTR + KWOFF + k0))[off8];
            *(uint4*)&Bsh[fr * 72 + off8 * 8] = v;
        }
        __syncthreads();

        #pragma unroll
        for (int ks = 0; ks < 64; ks += 32) {
            bf16x8 af[4], bf_[2];
            #pragma unroll
            for (int t = 0; t < 4; ++t)
                af[t]  = *(const bf16x8*)&Ash[(wmb + t * 16 + l16) * 72 + ks + quad * 8];
            #pragma unroll
            for (int t = 0; t < 2; ++t)
                bf_[t] = *(const bf16x8*)&Bsh[(wnb + t * 16 + l16) * 72 + ks + quad * 8];
            #pragma unroll
            for (int i = 0; i < 4; ++i)
                #pragma unroll
                for (int j = 0; j < 2; ++j)
                    acc[i][j] = __builtin_amdgcn_mfma_f32_16x16x32_bf16(
                        af[i], bf_[j], acc[i][j], 0, 0, 0);
        }
        __syncthreads();
    }

    // Epilogues. C/D layout: f(col) = l16, m(row) = quad*4 + reg.
    // m = m_base + wmb + i*16 + quad*4 + r;  f = n_base + wnb + j*16 + l16.
    if constexpr (MODE == MODE_STORE) {             // H store (RPB==1)
        #pragma unroll
        for (int j = 0; j < 2; ++j) {
            int f = n_base + wnb + j * 16 + l16;
            #pragma unroll
            for (int i = 0; i < 4; ++i)
                #pragma unroll
                for (int r = 0; r < 4; ++r) {
                    int m = m_base + wmb + i * 16 + quad * 4 + r;
                    *(unsigned short*)&Hbuf[(size_t)m * 512 + f] = f2b(acc[i][j][r]);
                }
        }
    } else if constexpr (MODE == MODE_STATS) {
        float* red = (float*)Ash;                   // Ash dead past last barrier
        for (int i = tid; i < RPB * 128; i += 256) red[i] = 0.f;
        __syncthreads();
        #pragma unroll
        for (int j = 0; j < 2; ++j) {
            int fl = wnb + j * 16 + l16;            // 0..63
            float sr[4] = {0.f,0.f,0.f,0.f}, qr[4] = {0.f,0.f,0.f,0.f};
            #pragma unroll
            for (int i = 0; i < 4; ++i) {
                float h = 0.f;
                if constexpr (HADD) {               // RPB==4: one b per (i,quad)
                    int b = b0 + (wmb >> 2) + i * 4 + quad;
                    h = __bfloat162float(Hbuf[(size_t)b * 512 + n_base + fl]);
                }
                #pragma unroll
                for (int r = 0; r < 4; ++r) {
                    float v = acc[i][j][r] + h;
                    sr[r] += v; qr[r] += v * v;
                }
            }
            #pragma unroll
            for (int r = 0; r < 4; ++r) {
                int kk = r % RPB;
                atomicAdd(&red[kk * 64 + fl], sr[r]);
                atomicAdd(&red[RPB * 64 + kk * 64 + fl], qr[r]);
            }
        }
        __syncthreads();
        for (int idx = tid; idx < RPB * 64; idx += 256) {
            int kw = KOFF + (idx >> 6);
            int f  = n_base + (idx & 63);
            atomicAdd(&accum[kw * 512 + f], red[idx]);
            atomicAdd(&accum[3072 + kw * 512 + f], red[RPB * 64 + idx]);
        }
    } else if constexpr (MODE == MODE_MIN1) {       // RPB==2, windows 0,1
        #pragma unroll
        for (int j = 0; j < 2; ++j) {
            int f = n_base + wnb + j * 16 + l16;
            float a0 = coef[f],        c0 = coef[3072 + f];
            float a1 = coef[512 + f],  c1 = coef[3072 + 512 + f];
            #pragma unroll
            for (int i = 0; i < 4; ++i) {
                #pragma unroll
                for (int rp = 0; rp < 2; ++rp) {
                    int m = m_base + wmb + i * 16 + quad * 4 + rp * 2;
                    float v0 = fmaxf(a0 * acc[i][j][rp * 2]     + c0, 0.f);
                    float v1 = fmaxf(a1 * acc[i][j][rp * 2 + 1] + c1, 0.f);
                    *(unsigned short*)&min1[(size_t)(m >> 1) * 512 + f] =
                        f2b(fminf(v0, v1));
                }
            }
        }
    } else {  // MODE_FINAL: RPB==4, windows 2..5 in r=0..3
        float dotp[4] = {0.f, 0.f, 0.f, 0.f};
        #pragma unroll
        for (int j = 0; j < 2; ++j) {
            int f = n_base + wnb + j * 16 + l16;
            float a[4], c[4];
            #pragma unroll
            for (int r = 0; r < 4; ++r) {
                a[r] = coef[(2 + r) * 512 + f];
                c[r] = coef[3072 + (2 + r) * 512 + f];
            }
            float fw = fcw[f];
            #pragma unroll
            for (int i = 0; i < 4; ++i) {
                int b = b0 + (wmb >> 2) + i * 4 + quad;
                float h = 0.f;
                if constexpr (HADD)
                    h = __bfloat162float(Hbuf[(size_t)b * 512 + f]);
                float mv = 1e30f;
                #pragma unroll
                for (int r = 0; r < 4; ++r)
                    mv = fminf(mv, fmaxf(a[r] * (acc[i][j][r] + h) + c[r], 0.f));
                mv = fminf(mv, __bfloat162float(min1[(size_t)b * 512 + f]));
                dotp[i] += mv * fw;
            }
        }
        #pragma unroll
        for (int i = 0; i < 4; ++i) {
            float v = dotp[i];
            #pragma unroll
            for (int s = 8; s >= 1; s >>= 1) v += __shfl_xor(v, s);
            if (l16 == 0) {
                int b = b0 + (wmb >> 2) + i * 4 + quad;
                atomicAdd(&outacc[b], v);
            }
        }
    }
}

__global__ void bncoef_kernel(const float* __restrict__ accum,
                              const float* __restrict__ g1, const float* __restrict__ be1,
                              const float* __restrict__ g2, const float* __restrict__ be2,
                              float* __restrict__ coef)
{
    int id = blockIdx.x * 256 + threadIdx.x;
    if (id >= 3072) return;
    int kw = id >> 9, f = id & 511;
    float mean = accum[id] * (1.f / BATCH);
    float var  = accum[3072 + id] * (1.f / BATCH) - mean * mean;
    float g  = kw < 2 ? g1[f] : g2[f];
    float be = kw < 2 ? be1[f] : be2[f];
    float a  = g * rsqrtf(var + 1e-5f);
    coef[id] = a;
    coef[3072 + id] = be - a * mean;
}

__global__ void finish_kernel(const float* __restrict__ outacc,
                              const float* __restrict__ fcb, float* __restrict__ out)
{
    int b = blockIdx.x * 256 + threadIdx.x;
    if (b < BATCH)
        out[b] = outacc[b] + fcb[0];
}

extern "C" void kernel_launch(void* const* d_in, const int* in_sizes, int n_in,
                              void* d_out, int out_size, void* d_ws, size_t ws_size,
                              hipStream_t stream)
{
    (void)in_sizes; (void)n_in; (void)out_size;
    const int*   x    = (const int*)  d_in[0];
    const float* embR = (const float*)d_in[2];    // 50000 x 256 f32
    const float* embV = (const float*)d_in[3];    // 50000 x 256 f32
    const float* W1   = (const float*)d_in[4];    // 512 x 2 x 256 f32
    const float* g1   = (const float*)d_in[6];
    const float* be1  = (const float*)d_in[7];
    const float* W2   = (const float*)d_in[8];    // 512 x 5 x 256 f32
    const float* g2   = (const float*)d_in[10];
    const float* be2  = (const float*)d_in[11];
    const float* fcw  = (const float*)d_in[12];   // 512 f32
    const float* fcb  = (const float*)d_in[13];

    char* wsb = (char*)d_ws;
    float* accum  = (float*)wsb;                          //       0: 24 KB
    float* coef   = accum + 6144;                         //   24576: 24 KB
    float* outacc = coef + 6144;                          //   49152: 128 KB
    bf16*  Wbf1   = (bf16*)(wsb + 180224);                //  512 KB
    bf16*  Wbf2   = (bf16*)(wsb + 704512);                // 1.25 MB
    bf16*  Hbuf   = (bf16*)(wsb + 2015232);               // 32 MB (B*512 bf16)
    bf16*  min1   = (bf16*)(wsb + 35569664);              // 32 MB -> 69124096
    bf16*  embRb1 = (bf16*)(wsb + 69124096);              // 24.4 MB (tier1 only)
    bf16*  embVb1 = (bf16*)(wsb + 94724096);              // -> 120324096
    bf16*  min3   = (bf16*)(wsb + 2015232);               // tier3 (H slot)

    const int tier = (ws_size >= 120324096) ? 1
                   : (ws_size >=  69124096) ? 2 : 3;

    hipMemsetAsync(accum, 0, 6144 * sizeof(float), stream);
    hipMemsetAsync(outacc, 0, BATCH * sizeof(float), stream);
    cvt_kernel<<<256, 256, 0, stream>>>(W1, (unsigned short*)Wbf1, 65536);
    cvt_kernel<<<640, 256, 0, stream>>>(W2, (unsigned short*)Wbf2, 163840);

    // Grids: (m_tiles/8 supers) x 8 n-tiles x 8 rows = m_tiles * 8 blocks.
    if (tier == 1) {
        cvt_kernel<<<12500, 256, 0, stream>>>(embR, (unsigned short*)embRb1, 3200000);
        cvt_kernel<<<12500, 256, 0, stream>>>(embV, (unsigned short*)embVb1, 3200000);
        gemm_kernel<768, 1280, 0, 1, MODE_STORE, false, false><<<2048, 256, 0, stream>>>(
            x, embRb1, embVb1, Wbf2, nullptr, nullptr, nullptr, Hbuf, nullptr, nullptr);
        gemm_kernel<512, 512, 0, 2, MODE_STATS, false, false><<<4096, 256, 0, stream>>>(
            x, embRb1, embVb1, Wbf1, accum, nullptr, nullptr, nullptr, nullptr, nullptr);
        gemm_kernel<512, 1280, 768, 4, MODE_STATS, true, false><<<8192, 256, 0, stream>>>(
            x, embRb1, embVb1, Wbf2, accum, nullptr, nullptr, Hbuf, nullptr, nullptr);
        bncoef_kernel<<<12, 256, 0, stream>>>(accum, g1, be1, g2, be2, coef);
        gemm_kernel<512, 512, 0, 2, MODE_MIN1, false, false><<<4096, 256, 0, stream>>>(
            x, embRb1, embVb1, Wbf1, nullptr, coef, min1, nullptr, nullptr, nullptr);
        gemm_kernel<512, 1280, 768, 4, MODE_FINAL, true, false><<<8192, 256, 0, stream>>>(
            x, embRb1, embVb1, Wbf2, nullptr, coef, min1, Hbuf, fcw, outacc);
    } else if (tier == 2) {
        gemm_kernel<768, 1280, 0, 1, MODE_STORE, false, true><<<2048, 256, 0, stream>>>(
            x, embR, embV, Wbf2, nullptr, nullptr, nullptr, Hbuf, nullptr, nullptr);
        gemm_kernel<512, 512, 0, 2, MODE_STATS, false, true><<<4096, 256, 0, stream>>>(
            x, embR, embV, Wbf1, accum, nullptr, nullptr, nullptr, nullptr, nullptr);
        gemm_kernel<512, 1280, 768, 4, MODE_STATS, true, true><<<8192, 256, 0, stream>>>(
            x, embR, embV, Wbf2, accum, nullptr, nullptr, Hbuf, nullptr, nullptr);
        bncoef_kernel<<<12, 256, 0, stream>>>(accum, g1, be1, g2, be2, coef);
        gemm_kernel<512, 512, 0, 2, MODE_MIN1, false, true><<<4096, 256, 0, stream>>>(
            x, embR, embV, Wbf1, nullptr, coef, min1, nullptr, nullptr, nullptr);
        gemm_kernel<512, 1280, 768, 4, MODE_FINAL, true, true><<<8192, 256, 0, stream>>>(
            x, embR, embV, Wbf2, nullptr, coef, min1, Hbuf, fcw, outacc);
    } else {  // tier3: monolithic K=1280 fallback (35.6 MB)
        gemm_kernel<512, 512, 0, 2, MODE_STATS, false, true><<<4096, 256, 0, stream>>>(
            x, embR, embV, Wbf1, accum, nullptr, nullptr, nullptr, nullptr, nullptr);
        gemm_kernel<1280, 1280, 0, 4, MODE_STATS, false, true><<<8192, 256, 0, stream>>>(
            x, embR, embV, Wbf2, accum, nullptr, nullptr, nullptr, nullptr, nullptr);
        bncoef_kernel<<<12, 256, 0, stream>>>(accum, g1, be1, g2, be2, coef);
        gemm_kernel<512, 512, 0, 2, MODE_MIN1, false, true><<<4096, 256, 0, stream>>>(
            x, embR, embV, Wbf1, nullptr, coef, min3, nullptr, nullptr, nullptr);
        gemm_kernel<1280, 1280, 0, 4, MODE_FINAL, false, true><<<8192, 256, 0, stream>>>(
            x, embR, embV, Wbf2, nullptr, coef, min3, nullptr, fcw, outacc);
    }
    finish_kernel<<<128, 256, 0, stream>>>(outacc, fcb, (float*)d_out);
}